// Round 8
// baseline (288.348 us; speedup 1.0000x reference)
//
#include <hip/hip_runtime.h>
#include <stdint.h>

#define Bsz 4
#define Lsz 512
#define Dsz 768
#define Wsz 12
#define LWsz (Lsz * Wsz)        /* 6144  */
#define Nh   (Bsz * Lsz * Dsz)  /* 1572864 */
#define Npw  (2 * Dsz * Dsz)    /* 1179648 */
#define Npb  (2 * Dsz)          /* 1536 */
#define Now  (Dsz * 3 * Dsz)    /* 1769472 */
#define Nob  (Dsz)              /* 768 */
#define Nbt2 (Dsz * Wsz * Dsz)  /* 7077888 */
#define Nsp  (Bsz * Lsz * Wsz * 2) /* 49152 */
#define Nrp  (Bsz * Lsz * 2 * Dsz) /* 3145728 */
#define Nrc  (Bsz * Lsz * Wsz * Dsz) /* 18874368 */
#define Kconv (Wsz * Dsz)       /* 9216 */

#define POFF1 Nh
#define POFF2 (Nh + Npw)
#define POFF3 (Nh + Npw + Npb)
#define POFF4 (Nh + Npw + Npb + Now)
#define PTOT  (Nh + Npw + Npb + Now + Nob)

/* pack_fused block ranges */
#define PB_ALL  ((PTOT / 4 + 255) / 256)          /* 4418 */
#define PB_CONV ((Nbt2 / Wsz) / 256)              /* 589824/256 = 2304 */
#define PB_SPAN ((Nsp + 255) / 256)               /* 192 */
#define PB_TOT  (PB_ALL + PB_CONV + PB_SPAN)

typedef __attribute__((ext_vector_type(8))) __bf16 bf16x8;
typedef __attribute__((ext_vector_type(4))) float f32x4;
typedef unsigned short u16;
typedef unsigned int u32;

#if __has_builtin(__builtin_amdgcn_mfma_f32_16x16x32_bf16)
#define HAVE_MFMA950 1
#else
#define HAVE_MFMA950 0
#endif

#if __has_builtin(__builtin_amdgcn_global_load_lds)
#define HAVE_GLL 1
#else
#define HAVE_GLL 0
#endif

static __device__ __forceinline__ f32x4 mfma_bf16(bf16x8 a, bf16x8 b, f32x4 c) {
#if HAVE_MFMA950
    return __builtin_amdgcn_mfma_f32_16x16x32_bf16(a, b, c, 0, 0, 0);
#else
    return c;  // never executed on MI355X
#endif
}

static __device__ __forceinline__ void gll16(const u16* g, u16* l) {
#if HAVE_GLL
    __builtin_amdgcn_global_load_lds(
        (const __attribute__((address_space(1))) u32*)g,
        (__attribute__((address_space(3))) u32*)l, 16, 0, 0);
#else
    *(uint4*)l = *(const uint4*)g;  // never executed on MI355X
#endif
}

static __device__ __forceinline__ float bf2f(u16 u) {
    union { u32 i; float f; } c; c.i = ((u32)u) << 16; return c.f;
}
static __device__ __forceinline__ u16 f2bf(float f) {
    union { float f; u32 i; } c; c.f = f;
    u32 u = c.i + 0x7FFFu + ((c.i >> 16) & 1u);
    return (u16)(u >> 16);
}

// ---------- dtype detection (verified R3..R7) ----------
__global__ void detect_k(const u32* __restrict__ hw, const u32* __restrict__ sw,
                         int* __restrict__ flags) {
    __shared__ int cnt[2];
    if (threadIdx.x == 0) { cnt[0] = 0; cnt[1] = 0; }
    __syncthreads();
    int c0 = 0;
    for (int i = threadIdx.x; i < 2048; i += 256) {
        u32 e = (hw[i] >> 23) & 0xFFu;
        if (e >= 118u && e <= 130u) c0++;
    }
    int c1 = 0;
    for (int i = threadIdx.x; i < 512; i += 256)
        if (sw[2 * i + 1] == 0u) c1++;
    atomicAdd(&cnt[0], c0);
    atomicAdd(&cnt[1], c1);
    __syncthreads();
    if (threadIdx.x == 0) {
        flags[0] = (cnt[0] > 1024) ? 1 : 0;
        flags[1] = (cnt[1] >= 512) ? 1 : 0;
    }
}

// ---------- fused pack: pack_all + pack_conv(coalesced) + pack_span --------
__global__ __launch_bounds__(256) void pack_fused(
        const void* __restrict__ s0, const void* __restrict__ s1,
        const void* __restrict__ s2, const void* __restrict__ s3,
        const void* __restrict__ s4, u16* __restrict__ dst,
        const void* __restrict__ convsrc, u16* __restrict__ cdst,
        const int* __restrict__ sp, int* __restrict__ spdst,
        const int* __restrict__ flags) {
    const int blk = blockIdx.x;
    if (blk < PB_ALL) {
        int i4 = blk * 256 + threadIdx.x;
        if (i4 >= PTOT / 4) return;
        int i = i4 * 4;
        const void* src; int off;
        if (i < POFF1)      { src = s0; off = i; }
        else if (i < POFF2) { src = s1; off = i - POFF1; }
        else if (i < POFF3) { src = s2; off = i - POFF2; }
        else if (i < POFF4) { src = s3; off = i - POFF3; }
        else                { src = s4; off = i - POFF4; }
        ushort4 o;
        if (flags[0]) {
            const float* f = (const float*)src + off;
            o.x = f2bf(f[0]); o.y = f2bf(f[1]); o.z = f2bf(f[2]); o.w = f2bf(f[3]);
        } else {
            o = *(const ushort4*)((const u16*)src + off);
        }
        *(ushort4*)(dst + i) = o;
    } else if (blk < PB_ALL + PB_CONV) {
        int g = (blk - PB_ALL) * 256 + threadIdx.x;   // [0, 589824)
        int o = g / Dsz;
        int c = g - o * Dsz;
        if (flags[0]) {
            const float* s = (const float*)convsrc + ((size_t)o * Dsz + c) * Wsz;
            float v[12];
            *(float4*)&v[0] = *(const float4*)(s + 0);   // 48B-stride: 16B-aligned
            *(float4*)&v[4] = *(const float4*)(s + 4);
            *(float4*)&v[8] = *(const float4*)(s + 8);
#pragma unroll
            for (int j = 0; j < Wsz; ++j)
                cdst[((size_t)o * Wsz + j) * Dsz + c] = f2bf(v[j]);
        } else {
            const u16* s = (const u16*)convsrc + ((size_t)o * Dsz + c) * Wsz;
            u16 v[12];
            *(uint2*)&v[0] = *(const uint2*)(s + 0);     // 24B-stride: 8B-aligned
            *(uint2*)&v[4] = *(const uint2*)(s + 4);
            *(uint2*)&v[8] = *(const uint2*)(s + 8);
#pragma unroll
            for (int j = 0; j < Wsz; ++j)
                cdst[((size_t)o * Wsz + j) * Dsz + c] = v[j];
        }
    } else {
        int i = (blk - PB_ALL - PB_CONV) * 256 + threadIdx.x;
        if (i >= Nsp) return;
        int v = flags[1] ? sp[2 * i] : sp[i];
        v = v < 0 ? 0 : (v > Lsz - 1 ? Lsz - 1 : v);
        spdst[i] = v;
    }
}

// ===== MFMA GEMMs: 128x128 tile, gll staging, double-buffered LDS ==========
// __launch_bounds__(256, 4): min 4 waves/EU caps unified VGPR+AGPR at 128
// (R7 measured: 76 arch + 64 acc = 140 -> 2 waves/SIMD -> 23% occupancy,
// the latency-hiding bottleneck). Essential live set ~116-125 regs -> fits.
#define MF_IDS()                                                          \
    const int tid = threadIdx.x;                                          \
    const int lane = tid & 63;                                            \
    const int wave = tid >> 6;                                            \
    const int wm = wave & 1, wn = wave >> 1;                              \
    const int lcol = lane & 15;                                           \
    const int quad = lane >> 4;                                           \
    const int sr = tid >> 2;                                              \
    const int sc = (tid & 3) * 8;                                         \
    f32x4 acc[4][4] = {};

#define MF_MFMA_BUF(cur)                                                  \
    do {                                                                  \
        const u16* Ab = lds_a + (cur) * 4096;                             \
        const u16* Bb = lds_b + (cur) * 4096;                             \
        bf16x8 af[4], bfr[4];                                             \
        _Pragma("unroll")                                                 \
        for (int _i = 0; _i < 4; ++_i)                                    \
            af[_i] = *(const bf16x8*)&Ab[(wm * 64 + _i * 16 + lcol) * 32 + quad * 8]; \
        _Pragma("unroll")                                                 \
        for (int _j = 0; _j < 4; ++_j)                                    \
            bfr[_j] = *(const bf16x8*)&Bb[(wn * 64 + _j * 16 + lcol) * 32 + quad * 8]; \
        _Pragma("unroll")                                                 \
        for (int _i = 0; _i < 4; ++_i)                                    \
            _Pragma("unroll")                                             \
            for (int _j = 0; _j < 4; ++_j)                                \
                acc[_i][_j] = mfma_bf16(af[_i], bfr[_j], acc[_i][_j]);    \
    } while (0)

// Swizzled variant (mgemm_out): rule-21 involution; R5 verified conflicts->0.
#define MF_MFMA_BUF_SWZ(cur)                                              \
    do {                                                                  \
        const u16* Ab = lds_a + (cur) * 4096;                             \
        const u16* Bb = lds_b + (cur) * 4096;                             \
        const int qx8 = (quad ^ ((lcol >> 1) & 3)) * 8;                   \
        bf16x8 af[4], bfr[4];                                             \
        _Pragma("unroll")                                                 \
        for (int _i = 0; _i < 4; ++_i)                                    \
            af[_i] = *(const bf16x8*)&Ab[(wm * 64 + _i * 16 + lcol) * 32 + qx8]; \
        _Pragma("unroll")                                                 \
        for (int _j = 0; _j < 4; ++_j)                                    \
            bfr[_j] = *(const bf16x8*)&Bb[(wn * 64 + _j * 16 + lcol) * 32 + qx8]; \
        _Pragma("unroll")                                                 \
        for (int _i = 0; _i < 4; ++_i)                                    \
            _Pragma("unroll")                                             \
            for (int _j = 0; _j < 4; ++_j)                                \
                acc[_i][_j] = mfma_bf16(af[_i], bfr[_j], acc[_i][_j]);    \
    } while (0)

// ---------- Launch A: convc [0,1152) + proj [1152,1344) in ONE dispatch -----
__global__ __launch_bounds__(256, 4) void mgemm_pc(const u16* __restrict__ H,
                                                   const u16* __restrict__ Bt2,
                                                   const u16* __restrict__ PW,
                                                   const u16* __restrict__ PB,
                                                   u16* __restrict__ Cv,
                                                   u16* __restrict__ RP) {
    __shared__ __align__(16) u16 lds_a[2 * 4096];
    __shared__ __align__(16) u16 lds_b[2 * 4096];
    MF_IDS();
    const int d = blockIdx.x;
    if (d < 1152) {
        // ----- convc: bijective XCD-chunk swizzle, j-major / bn / bm-fastest
        const int t = (d & 7) * 144 + (d >> 3);
        const int j = t / 96;
        const int rem = t - j * 96;
        const int bn = (rem >> 4) * 128;
        const int bm = (rem & 15) * 128;
        const int row0 = bm + sr, row1 = row0 + 64;
        const int l0 = row0 & (Lsz - 1), l1 = row1 & (Lsz - 1);
        const u16* a0 = H + (size_t)(row0 + j) * 768 + sc;
        const u16* a1 = H + (size_t)(row1 + j) * 768 + sc;
        const u16* b0 = Bt2 + (size_t)(bn + sr) * Kconv + (size_t)j * 768 + sc;
        const bool v0 = (l0 + j < Lsz), v1 = (l1 + j < Lsz);
        const uint4 zero = {0u, 0u, 0u, 0u};
        if (!v0) { *(uint4*)(lds_a + tid * 8) = zero; *(uint4*)(lds_a + 4096 + tid * 8) = zero; }
        if (!v1) { *(uint4*)(lds_a + 2048 + tid * 8) = zero; *(uint4*)(lds_a + 4096 + 2048 + tid * 8) = zero; }
        auto stage = [&](int buf, int kb) {
            u16* base_a = lds_a + buf * 4096 + tid * 8;
            u16* base_b = lds_b + buf * 4096 + tid * 8;
            if (v0) gll16(a0 + kb, base_a);
            if (v1) gll16(a1 + kb, base_a + 2048);
            gll16(b0 + kb, base_b);
            gll16(b0 + (size_t)64 * Kconv + kb, base_b + 2048);
        };
        stage(0, 0);
        __syncthreads();
        for (int kb = 0; kb < 768; kb += 32) {
            const int cur = (kb >> 5) & 1;
            if (kb + 32 < 768) stage(cur ^ 1, kb + 32);
            MF_MFMA_BUF(cur);
            __syncthreads();
        }
#pragma unroll
        for (int i = 0; i < 4; ++i)
#pragma unroll
            for (int jj = 0; jj < 4; ++jj) {
                int col = bn + wn * 64 + jj * 16 + lcol;
#pragma unroll
                for (int r = 0; r < 4; ++r) {
                    int row = bm + wm * 64 + i * 16 + quad * 4 + r;
                    Cv[((size_t)row * Wsz + j) * 768 + col] = f2bf(acc[i][jj][r]);
                }
            }
    } else {
        // ----- proj: rproj = relu(h @ proj_w^T + proj_b); M2048 N1536 K768
        const int e = d - 1152;
        const int bm = (e & 15) * 128;
        const int bn = (e >> 4) * 128;
        const u16* a0 = H + (size_t)(bm + sr) * 768 + sc;
        const u16* b0 = PW + (size_t)(bn + sr) * 768 + sc;
        auto stage = [&](int buf, int kb) {
            u16* base_a = lds_a + buf * 4096 + tid * 8;
            u16* base_b = lds_b + buf * 4096 + tid * 8;
            gll16(a0 + kb, base_a);
            gll16(a0 + (size_t)64 * 768 + kb, base_a + 2048);
            gll16(b0 + kb, base_b);
            gll16(b0 + (size_t)64 * 768 + kb, base_b + 2048);
        };
        stage(0, 0);
        __syncthreads();
        for (int kb = 0; kb < 768; kb += 32) {
            const int cur = (kb >> 5) & 1;
            if (kb + 32 < 768) stage(cur ^ 1, kb + 32);
            MF_MFMA_BUF(cur);
            __syncthreads();
        }
#pragma unroll
        for (int i = 0; i < 4; ++i)
#pragma unroll
            for (int j = 0; j < 4; ++j) {
                int col = bn + wn * 64 + j * 16 + lcol;
                float bv = bf2f(PB[col]);
#pragma unroll
                for (int r = 0; r < 4; ++r) {
                    int row = bm + wm * 64 + i * 16 + quad * 4 + r;
                    float v = acc[i][j][r] + bv;
                    RP[(size_t)row * 1536 + col] = f2bf(v > 0.f ? v : 0.f);
                }
            }
    }
}

// ---------- Launch B: p01 [0,192) + cumsum_relu [192,960) in ONE dispatch ---
__global__ __launch_bounds__(256, 4) void mgemm_p01c(const u16* __restrict__ RP,
                                                     const u16* __restrict__ W,
                                                     const u16* __restrict__ bias,
                                                     float* __restrict__ P,
                                                     u16* __restrict__ Cv) {
    __shared__ __align__(16) u16 lds_a[2 * 4096];
    __shared__ __align__(16) u16 lds_b[2 * 4096];
    MF_IDS();
    const int d = blockIdx.x;
    if (d < 192) {
        // ----- p01: P[z] = rproj[:, z*768:] @ out_w[:, z*768:]^T (+bias z=0)
        const int z = d >> 1 >= 48 ? 1 : 0;      // d in [0,96)->z0, [96,192)->z1
        const int e = d - z * 96;                // 0..95
        const int bm = (e & 15) * 128;
        const int bn = (e >> 4) * 128;
        const u16* a0 = RP + (size_t)(bm + sr) * 1536 + z * 768 + sc;
        const u16* b0 = W + (size_t)(bn + sr) * 2304 + z * 768 + sc;
        auto stage = [&](int buf, int kb) {
            u16* base_a = lds_a + buf * 4096 + tid * 8;
            u16* base_b = lds_b + buf * 4096 + tid * 8;
            gll16(a0 + kb, base_a);
            gll16(a0 + (size_t)64 * 1536 + kb, base_a + 2048);
            gll16(b0 + kb, base_b);
            gll16(b0 + (size_t)64 * 2304 + kb, base_b + 2048);
        };
        stage(0, 0);
        __syncthreads();
        for (int kb = 0; kb < 768; kb += 32) {
            const int cur = (kb >> 5) & 1;
            if (kb + 32 < 768) stage(cur ^ 1, kb + 32);
            MF_MFMA_BUF(cur);
            __syncthreads();
        }
        float* Pz = P + (size_t)z * 2048 * 768;
#pragma unroll
        for (int i = 0; i < 4; ++i)
#pragma unroll
            for (int j = 0; j < 4; ++j) {
                int col = bn + wn * 64 + j * 16 + lcol;
                float bv = (z == 0) ? bf2f(bias[col]) : 0.f;
#pragma unroll
                for (int r = 0; r < 4; ++r) {
                    int row = bm + wm * 64 + i * 16 + quad * 4 + r;
                    Pz[(size_t)row * 768 + col] = acc[i][j][r] + bv;
                }
            }
    } else {
        // ----- cumsum_relu: in-place running sum over j + relu on rconv
        int idx = (d - 192) * 256 + tid;         // exactly 768*256 = total
        int m = idx / (Dsz / 8);
        int c = (idx % (Dsz / 8)) * 8;
        u16* p = Cv + (size_t)m * Wsz * 768 + c;
        float s[8] = {0.f, 0.f, 0.f, 0.f, 0.f, 0.f, 0.f, 0.f};
#pragma unroll
        for (int j = 0; j < Wsz; ++j) {
            uint4 t = *(const uint4*)(p + (size_t)j * 768);
            const u16* q = (const u16*)&t;
            uint4 o;
            u16* qo = (u16*)&o;
#pragma unroll
            for (int i = 0; i < 8; ++i) {
                s[i] += bf2f(q[i]);
                qo[i] = f2bf(s[i] > 0.f ? s[i] : 0.f);
            }
            *(uint4*)(p + (size_t)j * 768) = o;
        }
    }
}

// ---------- GEMM 3: out = relu(rconv_relu @ W3^T + P0[s0] + P1[s1]) ---------
__global__ __launch_bounds__(256, 4) void mgemm_out(const u16* __restrict__ RC,
                                                    const int* __restrict__ SPn,
                                                    const u16* __restrict__ W,
                                                    const float* __restrict__ P,
                                                    void* __restrict__ out,
                                                    const int* __restrict__ flags) {
    __shared__ __align__(16) u16 lds_a[2 * 4096];
    __shared__ __align__(16) u16 lds_b[2 * 4096];
    __shared__ u32 off0[128], off1[128];
    MF_IDS();
    const int scs = ((tid & 3) ^ ((sr >> 1) & 3)) * 8;
    const int d = blockIdx.x;
    const int t = (d & 7) * 144 + (d >> 3);   // d = 8q+r -> t = r*144+q, bijective
    const int bm = (t / 6) * 128;
    const int bn = (t % 6) * 128;
    if (tid < 128) {
        int n = bm + tid;
        int b = n / LWsz;
        off0[tid] = (u32)((b * Lsz + SPn[2 * n]) * 768);
        off1[tid] = (u32)((b * Lsz + SPn[2 * n + 1]) * 768);
    }
    const u16* a0 = RC + (size_t)(bm + sr) * 768 + scs;
    const u16* b0 = W + (size_t)(bn + sr) * 2304 + 1536 + scs;
    auto stage = [&](int buf, int kb) {
        u16* base_a = lds_a + buf * 4096 + tid * 8;
        u16* base_b = lds_b + buf * 4096 + tid * 8;
        gll16(a0 + kb, base_a);
        gll16(a0 + (size_t)64 * 768 + kb, base_a + 2048);
        gll16(b0 + kb, base_b);
        gll16(b0 + (size_t)64 * 2304 + kb, base_b + 2048);
    };
    stage(0, 0);
    __syncthreads();
    for (int kb = 0; kb < 768; kb += 32) {
        const int cur = (kb >> 5) & 1;
        if (kb + 32 < 768) stage(cur ^ 1, kb + 32);
        MF_MFMA_BUF_SWZ(cur);
        __syncthreads();
    }
    const float* P1 = P + (size_t)2048 * 768;
    const int isf32 = flags[0];
#pragma unroll
    for (int i = 0; i < 4; ++i)
#pragma unroll
        for (int j = 0; j < 4; ++j) {
            int col = bn + wn * 64 + j * 16 + lcol;
#pragma unroll
            for (int r = 0; r < 4; ++r) {
                int rl = wm * 64 + i * 16 + quad * 4 + r;
                int row = bm + rl;
                float v = acc[i][j][r] + P[(size_t)off0[rl] + col] + P1[(size_t)off1[rl] + col];
                v = v > 0.f ? v : 0.f;
                if (isf32) ((float*)out)[(size_t)row * 768 + col] = v;
                else       ((u16*)out)[(size_t)row * 768 + col] = f2bf(v);
            }
        }
}

extern "C" void kernel_launch(void* const* d_in, const int* in_sizes, int n_in,
                              void* d_out, int out_size, void* d_ws, size_t ws_size,
                              hipStream_t stream) {
    const void* h      = d_in[0];
    const void* span   = d_in[1];
    const void* proj_w = d_in[2];
    const void* proj_b = d_in[3];
    const void* conv_w = d_in[4];
    const void* out_w  = d_in[5];
    const void* out_b  = d_in[6];

    char* p = (char*)d_ws;
    int* flags = (int*)p;                 p += 64;
    u16* ch    = (u16*)p;                 p += (size_t)Nh   * 2;   // pack dst base
    u16* cpw   = (u16*)p;                 p += (size_t)Npw  * 2;
    u16* cpb   = (u16*)p;                 p += (size_t)Npb  * 2;
    u16* cow   = (u16*)p;                 p += (size_t)Now  * 2;
    u16* cob   = (u16*)p;                 p += (size_t)Nob  * 2;
    u16* bt2   = (u16*)p;                 p += (size_t)Nbt2 * 2;   // 14.2 MB
    u16* rproj = (u16*)p;                 p += (size_t)Nrp  * 2;
    u16* rconv = (u16*)p;                 p += (size_t)Nrc  * 2;
    int* cspan = (int*)p;
    // P (2 x 2048 x 768 f32 = 12.6 MB) aliases bt2: bt2 is dead after
    // mgemm_pc (convc part), and mgemm_p01c launches after it.
    float* Pbuf = (float*)bt2;

    detect_k<<<1, 256, 0, stream>>>((const u32*)h, (const u32*)span, flags);

    pack_fused<<<PB_TOT, 256, 0, stream>>>(h, proj_w, proj_b, out_w, out_b, ch,
                                           conv_w, bt2,
                                           (const int*)span, cspan, flags);

    mgemm_pc<<<1344, 256, 0, stream>>>(ch, bt2, cpw, cpb, rconv, rproj);
    mgemm_p01c<<<960, 256, 0, stream>>>(rproj, cow, cob, Pbuf, rconv);
    mgemm_out<<<1152, 256, 0, stream>>>(rconv, cspan, cow, Pbuf,
                                        d_out, flags);
}

// Round 9
// 256.428 us; speedup vs baseline: 1.1245x; 1.1245x over previous
//
#include <hip/hip_runtime.h>
#include <stdint.h>

#define Bsz 4
#define Lsz 512
#define Dsz 768
#define Wsz 12
#define LWsz (Lsz * Wsz)        /* 6144  */
#define Nh   (Bsz * Lsz * Dsz)  /* 1572864 */
#define Npw  (2 * Dsz * Dsz)    /* 1179648 */
#define Npb  (2 * Dsz)          /* 1536 */
#define Now  (Dsz * 3 * Dsz)    /* 1769472 */
#define Nob  (Dsz)              /* 768 */
#define Nbt2 (Dsz * Wsz * Dsz)  /* 7077888 */
#define Nsp  (Bsz * Lsz * Wsz * 2) /* 49152 */
#define Nrp  (Bsz * Lsz * 2 * Dsz) /* 3145728 */
#define Nrc  (Bsz * Lsz * Wsz * Dsz) /* 18874368 */
#define Kconv (Wsz * Dsz)       /* 9216 */

#define POFF1 Nh
#define POFF2 (Nh + Npw)
#define POFF3 (Nh + Npw + Npb)
#define POFF4 (Nh + Npw + Npb + Now)
#define PTOT  (Nh + Npw + Npb + Now + Nob)

/* pack_fused block ranges */
#define PB_ALL  ((PTOT / 4 + 255) / 256)          /* 4418 */
#define PB_CONV ((Nbt2 / Wsz) / 256)              /* 589824/256 = 2304 */
#define PB_SPAN ((Nsp + 255) / 256)               /* 192 */
#define PB_TOT  (PB_ALL + PB_CONV + PB_SPAN)

typedef __attribute__((ext_vector_type(8))) __bf16 bf16x8;
typedef __attribute__((ext_vector_type(4))) float f32x4;
typedef unsigned short u16;
typedef unsigned int u32;

#if __has_builtin(__builtin_amdgcn_mfma_f32_16x16x32_bf16)
#define HAVE_MFMA950 1
#else
#define HAVE_MFMA950 0
#endif

#if __has_builtin(__builtin_amdgcn_global_load_lds)
#define HAVE_GLL 1
#else
#define HAVE_GLL 0
#endif

static __device__ __forceinline__ f32x4 mfma_bf16(bf16x8 a, bf16x8 b, f32x4 c) {
#if HAVE_MFMA950
    return __builtin_amdgcn_mfma_f32_16x16x32_bf16(a, b, c, 0, 0, 0);
#else
    return c;  // never executed on MI355X
#endif
}

static __device__ __forceinline__ void gll16(const u16* g, u16* l) {
#if HAVE_GLL
    __builtin_amdgcn_global_load_lds(
        (const __attribute__((address_space(1))) u32*)g,
        (__attribute__((address_space(3))) u32*)l, 16, 0, 0);
#else
    *(uint4*)l = *(const uint4*)g;  // never executed on MI355X
#endif
}

static __device__ __forceinline__ float bf2f(u16 u) {
    union { u32 i; float f; } c; c.i = ((u32)u) << 16; return c.f;
}
static __device__ __forceinline__ u16 f2bf(float f) {
    union { float f; u32 i; } c; c.f = f;
    u32 u = c.i + 0x7FFFu + ((c.i >> 16) & 1u);
    return (u16)(u >> 16);
}

// ---------- dtype detection (verified R3..R7) ----------
__global__ void detect_k(const u32* __restrict__ hw, const u32* __restrict__ sw,
                         int* __restrict__ flags) {
    __shared__ int cnt[2];
    if (threadIdx.x == 0) { cnt[0] = 0; cnt[1] = 0; }
    __syncthreads();
    int c0 = 0;
    for (int i = threadIdx.x; i < 2048; i += 256) {
        u32 e = (hw[i] >> 23) & 0xFFu;
        if (e >= 118u && e <= 130u) c0++;
    }
    int c1 = 0;
    for (int i = threadIdx.x; i < 512; i += 256)
        if (sw[2 * i + 1] == 0u) c1++;
    atomicAdd(&cnt[0], c0);
    atomicAdd(&cnt[1], c1);
    __syncthreads();
    if (threadIdx.x == 0) {
        flags[0] = (cnt[0] > 1024) ? 1 : 0;
        flags[1] = (cnt[1] >= 512) ? 1 : 0;
    }
}

// ---------- fused pack: pack_all + pack_conv(coalesced) + pack_span --------
__global__ __launch_bounds__(256) void pack_fused(
        const void* __restrict__ s0, const void* __restrict__ s1,
        const void* __restrict__ s2, const void* __restrict__ s3,
        const void* __restrict__ s4, u16* __restrict__ dst,
        const void* __restrict__ convsrc, u16* __restrict__ cdst,
        const int* __restrict__ sp, int* __restrict__ spdst,
        const int* __restrict__ flags) {
    const int blk = blockIdx.x;
    if (blk < PB_ALL) {
        int i4 = blk * 256 + threadIdx.x;
        if (i4 >= PTOT / 4) return;
        int i = i4 * 4;
        const void* src; int off;
        if (i < POFF1)      { src = s0; off = i; }
        else if (i < POFF2) { src = s1; off = i - POFF1; }
        else if (i < POFF3) { src = s2; off = i - POFF2; }
        else if (i < POFF4) { src = s3; off = i - POFF3; }
        else                { src = s4; off = i - POFF4; }
        ushort4 o;
        if (flags[0]) {
            const float* f = (const float*)src + off;
            o.x = f2bf(f[0]); o.y = f2bf(f[1]); o.z = f2bf(f[2]); o.w = f2bf(f[3]);
        } else {
            o = *(const ushort4*)((const u16*)src + off);
        }
        *(ushort4*)(dst + i) = o;
    } else if (blk < PB_ALL + PB_CONV) {
        int g = (blk - PB_ALL) * 256 + threadIdx.x;   // [0, 589824)
        int o = g / Dsz;
        int c = g - o * Dsz;
        if (flags[0]) {
            const float* s = (const float*)convsrc + ((size_t)o * Dsz + c) * Wsz;
            float v[12];
            *(float4*)&v[0] = *(const float4*)(s + 0);   // 48B-stride: 16B-aligned
            *(float4*)&v[4] = *(const float4*)(s + 4);
            *(float4*)&v[8] = *(const float4*)(s + 8);
#pragma unroll
            for (int j = 0; j < Wsz; ++j)
                cdst[((size_t)o * Wsz + j) * Dsz + c] = f2bf(v[j]);
        } else {
            const u16* s = (const u16*)convsrc + ((size_t)o * Dsz + c) * Wsz;
            u16 v[12];
            *(uint2*)&v[0] = *(const uint2*)(s + 0);     // 24B-stride: 8B-aligned
            *(uint2*)&v[4] = *(const uint2*)(s + 4);
            *(uint2*)&v[8] = *(const uint2*)(s + 8);
#pragma unroll
            for (int j = 0; j < Wsz; ++j)
                cdst[((size_t)o * Wsz + j) * Dsz + c] = v[j];
        }
    } else {
        int i = (blk - PB_ALL - PB_CONV) * 256 + threadIdx.x;
        if (i >= Nsp) return;
        int v = flags[1] ? sp[2 * i] : sp[i];
        v = v < 0 ? 0 : (v > Lsz - 1 ? Lsz - 1 : v);
        spdst[i] = v;
    }
}

// ===== MFMA GEMMs: 128x128 tile, gll staging, double-buffered LDS ==========
// (R8 lesson: NO min-waves launch_bounds -- the 4x4-acc live set doesn't fit
// 128 unified regs; the allocator spills to scratch, +21 MB HBM traffic.)
#define MF_IDS()                                                          \
    const int tid = threadIdx.x;                                          \
    const int lane = tid & 63;                                            \
    const int wave = tid >> 6;                                            \
    const int wm = wave & 1, wn = wave >> 1;                              \
    const int lcol = lane & 15;                                           \
    const int quad = lane >> 4;                                           \
    const int sr = tid >> 2;                                              \
    const int sc = (tid & 3) * 8;                                         \
    f32x4 acc[4][4] = {};

#define MF_MFMA_BUF(cur)                                                  \
    do {                                                                  \
        const u16* Ab = lds_a + (cur) * 4096;                             \
        const u16* Bb = lds_b + (cur) * 4096;                             \
        bf16x8 af[4], bfr[4];                                             \
        _Pragma("unroll")                                                 \
        for (int _i = 0; _i < 4; ++_i)                                    \
            af[_i] = *(const bf16x8*)&Ab[(wm * 64 + _i * 16 + lcol) * 32 + quad * 8]; \
        _Pragma("unroll")                                                 \
        for (int _j = 0; _j < 4; ++_j)                                    \
            bfr[_j] = *(const bf16x8*)&Bb[(wn * 64 + _j * 16 + lcol) * 32 + quad * 8]; \
        _Pragma("unroll")                                                 \
        for (int _i = 0; _i < 4; ++_i)                                    \
            _Pragma("unroll")                                             \
            for (int _j = 0; _j < 4; ++_j)                                \
                acc[_i][_j] = mfma_bf16(af[_i], bfr[_j], acc[_i][_j]);    \
    } while (0)

// ---------- Launch A: convc [0,1152) + proj [1152,1344) in ONE dispatch -----
__global__ __launch_bounds__(256) void mgemm_pc(const u16* __restrict__ H,
                                                const u16* __restrict__ Bt2,
                                                const u16* __restrict__ PW,
                                                const u16* __restrict__ PB,
                                                u16* __restrict__ Cv,
                                                u16* __restrict__ RP) {
    __shared__ __align__(16) u16 lds_a[2 * 4096];
    __shared__ __align__(16) u16 lds_b[2 * 4096];
    MF_IDS();
    const int d = blockIdx.x;
    if (d < 1152) {
        // ----- convc: bijective XCD-chunk swizzle, j-major / bn / bm-fastest
        const int t = (d & 7) * 144 + (d >> 3);
        const int j = t / 96;
        const int rem = t - j * 96;
        const int bn = (rem >> 4) * 128;
        const int bm = (rem & 15) * 128;
        const int row0 = bm + sr, row1 = row0 + 64;
        const int l0 = row0 & (Lsz - 1), l1 = row1 & (Lsz - 1);
        const u16* a0 = H + (size_t)(row0 + j) * 768 + sc;
        const u16* a1 = H + (size_t)(row1 + j) * 768 + sc;
        const u16* b0 = Bt2 + (size_t)(bn + sr) * Kconv + (size_t)j * 768 + sc;
        const bool v0 = (l0 + j < Lsz), v1 = (l1 + j < Lsz);
        const uint4 zero = {0u, 0u, 0u, 0u};
        if (!v0) { *(uint4*)(lds_a + tid * 8) = zero; *(uint4*)(lds_a + 4096 + tid * 8) = zero; }
        if (!v1) { *(uint4*)(lds_a + 2048 + tid * 8) = zero; *(uint4*)(lds_a + 4096 + 2048 + tid * 8) = zero; }
        auto stage = [&](int buf, int kb) {
            u16* base_a = lds_a + buf * 4096 + tid * 8;
            u16* base_b = lds_b + buf * 4096 + tid * 8;
            if (v0) gll16(a0 + kb, base_a);
            if (v1) gll16(a1 + kb, base_a + 2048);
            gll16(b0 + kb, base_b);
            gll16(b0 + (size_t)64 * Kconv + kb, base_b + 2048);
        };
        stage(0, 0);
        __syncthreads();
        for (int kb = 0; kb < 768; kb += 32) {
            const int cur = (kb >> 5) & 1;
            if (kb + 32 < 768) stage(cur ^ 1, kb + 32);
            MF_MFMA_BUF(cur);
            __syncthreads();
        }
#pragma unroll
        for (int i = 0; i < 4; ++i)
#pragma unroll
            for (int jj = 0; jj < 4; ++jj) {
                int col = bn + wn * 64 + jj * 16 + lcol;
#pragma unroll
                for (int r = 0; r < 4; ++r) {
                    int row = bm + wm * 64 + i * 16 + quad * 4 + r;
                    Cv[((size_t)row * Wsz + j) * 768 + col] = f2bf(acc[i][jj][r]);
                }
            }
    } else {
        // ----- proj: rproj = relu(h @ proj_w^T + proj_b); M2048 N1536 K768
        const int e = d - 1152;
        const int bm = (e & 15) * 128;
        const int bn = (e >> 4) * 128;
        const u16* a0 = H + (size_t)(bm + sr) * 768 + sc;
        const u16* b0 = PW + (size_t)(bn + sr) * 768 + sc;
        auto stage = [&](int buf, int kb) {
            u16* base_a = lds_a + buf * 4096 + tid * 8;
            u16* base_b = lds_b + buf * 4096 + tid * 8;
            gll16(a0 + kb, base_a);
            gll16(a0 + (size_t)64 * 768 + kb, base_a + 2048);
            gll16(b0 + kb, base_b);
            gll16(b0 + (size_t)64 * 768 + kb, base_b + 2048);
        };
        stage(0, 0);
        __syncthreads();
        for (int kb = 0; kb < 768; kb += 32) {
            const int cur = (kb >> 5) & 1;
            if (kb + 32 < 768) stage(cur ^ 1, kb + 32);
            MF_MFMA_BUF(cur);
            __syncthreads();
        }
#pragma unroll
        for (int i = 0; i < 4; ++i)
#pragma unroll
            for (int j = 0; j < 4; ++j) {
                int col = bn + wn * 64 + j * 16 + lcol;
                float bv = bf2f(PB[col]);
#pragma unroll
                for (int r = 0; r < 4; ++r) {
                    int row = bm + wm * 64 + i * 16 + quad * 4 + r;
                    float v = acc[i][j][r] + bv;
                    RP[(size_t)row * 1536 + col] = f2bf(v > 0.f ? v : 0.f);
                }
            }
    }
}

// ---------- Launch B: p01 [0,192) + cumsum_relu [192,960) in ONE dispatch ---
__global__ __launch_bounds__(256) void mgemm_p01c(const u16* __restrict__ RP,
                                                  const u16* __restrict__ W,
                                                  const u16* __restrict__ bias,
                                                  float* __restrict__ P,
                                                  u16* __restrict__ Cv) {
    __shared__ __align__(16) u16 lds_a[2 * 4096];
    __shared__ __align__(16) u16 lds_b[2 * 4096];
    MF_IDS();
    const int d = blockIdx.x;
    if (d < 192) {
        // ----- p01: P[z] = rproj[:, z*768:] @ out_w[:, z*768:]^T (+bias z=0)
        const int z = d >> 1 >= 48 ? 1 : 0;      // d in [0,96)->z0, [96,192)->z1
        const int e = d - z * 96;                // 0..95
        const int bm = (e & 15) * 128;
        const int bn = (e >> 4) * 128;
        const u16* a0 = RP + (size_t)(bm + sr) * 1536 + z * 768 + sc;
        const u16* b0 = W + (size_t)(bn + sr) * 2304 + z * 768 + sc;
        auto stage = [&](int buf, int kb) {
            u16* base_a = lds_a + buf * 4096 + tid * 8;
            u16* base_b = lds_b + buf * 4096 + tid * 8;
            gll16(a0 + kb, base_a);
            gll16(a0 + (size_t)64 * 1536 + kb, base_a + 2048);
            gll16(b0 + kb, base_b);
            gll16(b0 + (size_t)64 * 2304 + kb, base_b + 2048);
        };
        stage(0, 0);
        __syncthreads();
        for (int kb = 0; kb < 768; kb += 32) {
            const int cur = (kb >> 5) & 1;
            if (kb + 32 < 768) stage(cur ^ 1, kb + 32);
            MF_MFMA_BUF(cur);
            __syncthreads();
        }
        float* Pz = P + (size_t)z * 2048 * 768;
#pragma unroll
        for (int i = 0; i < 4; ++i)
#pragma unroll
            for (int j = 0; j < 4; ++j) {
                int col = bn + wn * 64 + j * 16 + lcol;
                float bv = (z == 0) ? bf2f(bias[col]) : 0.f;
#pragma unroll
                for (int r = 0; r < 4; ++r) {
                    int row = bm + wm * 64 + i * 16 + quad * 4 + r;
                    Pz[(size_t)row * 768 + col] = acc[i][j][r] + bv;
                }
            }
    } else {
        // ----- cumsum_relu: in-place running sum over j + relu on rconv
        int idx = (d - 192) * 256 + tid;         // exactly 768*256 = total
        int m = idx / (Dsz / 8);
        int c = (idx % (Dsz / 8)) * 8;
        u16* p = Cv + (size_t)m * Wsz * 768 + c;
        float s[8] = {0.f, 0.f, 0.f, 0.f, 0.f, 0.f, 0.f, 0.f};
#pragma unroll
        for (int j = 0; j < Wsz; ++j) {
            uint4 t = *(const uint4*)(p + (size_t)j * 768);
            const u16* q = (const u16*)&t;
            uint4 o;
            u16* qo = (u16*)&o;
#pragma unroll
            for (int i = 0; i < 8; ++i) {
                s[i] += bf2f(q[i]);
                qo[i] = f2bf(s[i] > 0.f ? s[i] : 0.f);
            }
            *(uint4*)(p + (size_t)j * 768) = o;
        }
    }
}

// ---------- GEMM 3: out = relu(rconv_relu @ W3^T + P0[s0] + P1[s1]) ---------
// M24576 N768 K768. NEW (R9): 512 threads / 8 waves per 128x128 block; each
// wave owns a 64x32 sub-tile -> acc[4][2] = 32 VGPRs (was 64). Unified live
// set ~100 < 128 -> 4 waves/SIMD occupancy WITHOUT a forcing bound (no spill,
// unlike R8). Staging: 512 thr x 16B = one gll per matrix per buffer.
// XCD swizzle + involution LDS swizzle (conflicts=0) carried over.
__global__ __launch_bounds__(512) void mgemm_out(const u16* __restrict__ RC,
                                                 const int* __restrict__ SPn,
                                                 const u16* __restrict__ W,
                                                 const float* __restrict__ P,
                                                 void* __restrict__ out,
                                                 const int* __restrict__ flags) {
    __shared__ __align__(16) u16 lds_a[2 * 4096];
    __shared__ __align__(16) u16 lds_b[2 * 4096];
    __shared__ u32 off0[128], off1[128];
    const int tid = threadIdx.x;
    const int lane = tid & 63;
    const int wave = tid >> 6;            // 0..7
    const int wm = wave & 1, wn = wave >> 1;   // wm: 0..1, wn: 0..3
    const int lcol = lane & 15;
    const int quad = lane >> 4;
    const int sr = tid >> 2;              // 0..127 (full tile height per gll)
    const int scs = ((tid & 3) ^ ((sr >> 1) & 3)) * 8;  // pre-swizzled source chunk
    f32x4 acc[4][2] = {};
    const int d = blockIdx.x;
    const int t = (d & 7) * 144 + (d >> 3);   // d = 8q+r -> t = r*144+q, bijective
    const int bm = (t / 6) * 128;
    const int bn = (t % 6) * 128;
    if (tid < 128) {
        int n = bm + tid;
        int b = n / LWsz;
        off0[tid] = (u32)((b * Lsz + SPn[2 * n]) * 768);
        off1[tid] = (u32)((b * Lsz + SPn[2 * n + 1]) * 768);
    }
    const u16* a0 = RC + (size_t)(bm + sr) * 768 + scs;
    const u16* b0 = W + (size_t)(bn + sr) * 2304 + 1536 + scs;
    auto stage = [&](int buf, int kb) {
        gll16(a0 + kb, lds_a + buf * 4096 + tid * 8);
        gll16(b0 + kb, lds_b + buf * 4096 + tid * 8);
    };
    stage(0, 0);
    __syncthreads();
    for (int kb = 0; kb < 768; kb += 32) {
        const int cur = (kb >> 5) & 1;
        if (kb + 32 < 768) stage(cur ^ 1, kb + 32);
        {
            const u16* Ab = lds_a + cur * 4096;
            const u16* Bb = lds_b + cur * 4096;
            const int qx8 = (quad ^ ((lcol >> 1) & 3)) * 8;  // involution reader
            bf16x8 af[4], bfr[2];
#pragma unroll
            for (int i = 0; i < 4; ++i)
                af[i] = *(const bf16x8*)&Ab[(wm * 64 + i * 16 + lcol) * 32 + qx8];
#pragma unroll
            for (int j = 0; j < 2; ++j)
                bfr[j] = *(const bf16x8*)&Bb[(wn * 32 + j * 16 + lcol) * 32 + qx8];
#pragma unroll
            for (int i = 0; i < 4; ++i)
#pragma unroll
                for (int j = 0; j < 2; ++j)
                    acc[i][j] = mfma_bf16(af[i], bfr[j], acc[i][j]);
        }
        __syncthreads();
    }
    const float* P1 = P + (size_t)2048 * 768;
    const int isf32 = flags[0];
#pragma unroll
    for (int i = 0; i < 4; ++i)
#pragma unroll
        for (int j = 0; j < 2; ++j) {
            int col = bn + wn * 32 + j * 16 + lcol;
#pragma unroll
            for (int r = 0; r < 4; ++r) {
                int rl = wm * 64 + i * 16 + quad * 4 + r;
                int row = bm + rl;
                float v = acc[i][j][r] + P[(size_t)off0[rl] + col] + P1[(size_t)off1[rl] + col];
                v = v > 0.f ? v : 0.f;
                if (isf32) ((float*)out)[(size_t)row * 768 + col] = v;
                else       ((u16*)out)[(size_t)row * 768 + col] = f2bf(v);
            }
        }
}

extern "C" void kernel_launch(void* const* d_in, const int* in_sizes, int n_in,
                              void* d_out, int out_size, void* d_ws, size_t ws_size,
                              hipStream_t stream) {
    const void* h      = d_in[0];
    const void* span   = d_in[1];
    const void* proj_w = d_in[2];
    const void* proj_b = d_in[3];
    const void* conv_w = d_in[4];
    const void* out_w  = d_in[5];
    const void* out_b  = d_in[6];

    char* p = (char*)d_ws;
    int* flags = (int*)p;                 p += 64;
    u16* ch    = (u16*)p;                 p += (size_t)Nh   * 2;   // pack dst base
    u16* cpw   = (u16*)p;                 p += (size_t)Npw  * 2;
    u16* cpb   = (u16*)p;                 p += (size_t)Npb  * 2;
    u16* cow   = (u16*)p;                 p += (size_t)Now  * 2;
    u16* cob   = (u16*)p;                 p += (size_t)Nob  * 2;
    u16* bt2   = (u16*)p;                 p += (size_t)Nbt2 * 2;   // 14.2 MB
    u16* rproj = (u16*)p;                 p += (size_t)Nrp  * 2;
    u16* rconv = (u16*)p;                 p += (size_t)Nrc  * 2;
    int* cspan = (int*)p;
    // P (2 x 2048 x 768 f32 = 12.6 MB) aliases bt2: bt2 is dead after
    // mgemm_pc (convc part), and mgemm_p01c launches after it.
    float* Pbuf = (float*)bt2;

    detect_k<<<1, 256, 0, stream>>>((const u32*)h, (const u32*)span, flags);

    pack_fused<<<PB_TOT, 256, 0, stream>>>(h, proj_w, proj_b, out_w, out_b, ch,
                                           conv_w, bt2,
                                           (const int*)span, cspan, flags);

    mgemm_pc<<<1344, 256, 0, stream>>>(ch, bt2, cpw, cpb, rconv, rproj);
    mgemm_p01c<<<960, 256, 0, stream>>>(rproj, cow, cob, Pbuf, rconv);
    mgemm_out<<<1152, 512, 0, stream>>>(rconv, cspan, cow, Pbuf,
                                        d_out, flags);
}